// Round 9
// baseline (769.512 us; speedup 1.0000x reference)
//
#include <hip/hip_runtime.h>
#include <hip/hip_bf16.h>
#include <math.h>

#define B_ 4
#define H_ 128
#define W_ 128
#define DIM_ 128
#define HEADS_ 8
#define DH_ 64
#define G_ 64
#define INNER_ 512
#define N_ 16384

typedef __attribute__((ext_vector_type(8))) short sh8;
typedef __attribute__((ext_vector_type(4))) float vf4;

// XPT tiled input layout (per plane): [row 0..129][c0 0..3][tile 0..519][8]
//   tile = kg*130 + px  (kg = channel-group of 8 within 32-chunk, px = padded col)
// slab per (row,c0) = 520*8 = 4160 shorts.  plane = 130*4*4160 = 2163200 shorts.
#define XPT_SLAB 4160
#define XPT_PLANE 2163200
// WT tiled weight layout (per plane): [tap 0..8][nt 0..7][c0 0..3][tile 0..511][8]
//   tile = kg*128 + oc(0..127), oc global = nt*128+oc.
#define WT_PLANE 1179648

__device__ __forceinline__ void gload16(const void* g, void* l) {
  __builtin_amdgcn_global_load_lds((const __attribute__((address_space(1))) void*)g,
                                   (__attribute__((address_space(3))) void*)l, 16, 0, 0);
}

__device__ __forceinline__ void split_bf16(float v, ushort& h, ushort& l) {
  __hip_bfloat16 hb = __float2bfloat16(v);
  float hf = __bfloat162float(hb);
  __hip_bfloat16 lb = __float2bfloat16(v - hf);
  h = *reinterpret_cast<ushort*>(&hb);
  l = *reinterpret_cast<ushort*>(&lb);
}

// ---- prep: pad+split batch-slice of x directly into XPT tiled hi/lo layout ----
// grid (8450, NB): blockIdx.y = batch within this launch.
__global__ __launch_bounds__(256) void pad_tile_kernel(const float* __restrict__ x,
                                                       ushort* __restrict__ xpth,
                                                       ushort* __restrict__ xptl) {
  const int bz = blockIdx.y;
  x += (size_t)bz * N_ * DIM_;
  xpth += (size_t)bz * XPT_PLANE;
  xptl += (size_t)bz * XPT_PLANE;
  const int idx = blockIdx.x * 256 + threadIdx.x;  // 2163200 exactly (8450 blocks)
  const int row = idx / (4 * XPT_SLAB);
  const int rem = idx % (4 * XPT_SLAB);
  const int c0i = rem / XPT_SLAB;
  const int t2 = rem % XPT_SLAB;
  const int tile = t2 >> 3, j = t2 & 7;
  const int kg = tile / 130, px = tile % 130;
  const int c = c0i * 32 + kg * 8 + j;
  float v = 0.0f;
  if (row >= 1 && row <= H_ && px >= 1 && px <= W_)
    v = x[((size_t)(row - 1) * W_ + (px - 1)) * DIM_ + c];
  ushort hh, ll;
  split_bf16(v, hh, ll);
  xpth[idx] = hh;
  xptl[idx] = ll;
}

// ---- prep: fx-branch weights into WT tiled layout (nt 4..7) ----
__global__ __launch_bounds__(256) void wfx_kernel(const float* __restrict__ Wfx,
                                                  ushort* __restrict__ wth,
                                                  ushort* __restrict__ wtl) {
  int idx = blockIdx.x * 256 + threadIdx.x;
  if (idx >= 9 * 512 * DIM_) return;
  const int c = idx & 127;
  const int ocf = (idx >> 7) & 511;
  const int tap = idx >> 16;
  float v = Wfx[((size_t)ocf * DIM_ + c) * 9 + tap];
  ushort hh, ll;
  split_bf16(v, hh, ll);
  const int nt = 4 + (ocf >> 7), oci = ocf & 127;
  const int c0i = c >> 5, kg = (c >> 3) & 3, j = c & 7;
  const size_t o = (((size_t)tap * 8 + nt) * 4 + c0i) * 4096 + ((size_t)kg * 128 + oci) * 8 + j;
  wth[o] = hh;
  wtl[o] = ll;
}

// ---- prep: composed x-branch weights (Ws/temp folded), WT tiled (nt 0..3) + bias bc ----
__global__ __launch_bounds__(256) void wcomp_kernel(const float* __restrict__ Wx,
                                                    const float* __restrict__ Ws,
                                                    const float* __restrict__ bx,
                                                    const float* __restrict__ bs,
                                                    const float* __restrict__ temperature,
                                                    ushort* __restrict__ wth,
                                                    ushort* __restrict__ wtl,
                                                    float* __restrict__ bc) {
  __shared__ float WxL[64][128];
  __shared__ float WsL[64][64];
  const int t = threadIdx.x;
  const int tap = blockIdx.x, h = blockIdx.y;
  for (int e = t; e < 8192; e += 256) {
    const int c2 = e >> 7, c = e & 127;
    WxL[c2][c] = Wx[((size_t)(h * 64 + c2) * DIM_ + c) * 9 + tap];
  }
  for (int e = t; e < 4096; e += 256) WsL[e >> 6][e & 63] = Ws[e];
  float tmp = fminf(fmaxf(temperature[h], 0.1f), 5.0f);
  const float invt = 1.0f / tmp;
  __syncthreads();
  for (int e = t; e < 8192; e += 256) {
    const int gg = e >> 7, c = e & 127;
    float s = 0.f;
#pragma unroll
    for (int c2 = 0; c2 < 64; ++c2) s = fmaf(WsL[gg][c2], WxL[c2][c], s);
    s *= invt;
    ushort hh, ll;
    split_bf16(s, hh, ll);
    const int ocp = h * 64 + gg;
    const int nt = ocp >> 7, oci = ocp & 127;
    const int c0i = c >> 5, kg = (c >> 3) & 3, j = c & 7;
    const size_t o = (((size_t)tap * 8 + nt) * 4 + c0i) * 4096 + ((size_t)kg * 128 + oci) * 8 + j;
    wth[o] = hh;
    wtl[o] = ll;
  }
  if (tap == 0 && t < 64) {
    float s = 0.f;
#pragma unroll
    for (int c2 = 0; c2 < 64; ++c2) s = fmaf(Ws[t * 64 + c2], bx[h * 64 + c2], s);
    bc[h * 64 + t] = (s + bs[t]) * invt;
  }
}

// ---- prep: Mqk[c][c'] = scale * sum_d Wq[d][c]*Wk[d][c'] ----
__global__ __launch_bounds__(256) void mqk_kernel(const float* __restrict__ Wq,
                                                  const float* __restrict__ Wk,
                                                  float* __restrict__ mqk) {
  const int idx = blockIdx.x * 256 + threadIdx.x;  // 4096
  const int c = idx >> 6, c2 = idx & 63;
  float s = 0.f;
#pragma unroll
  for (int d = 0; d < 64; ++d) s = fmaf(Wq[d * 64 + c], Wk[d * 64 + c2], s);
  mqk[idx] = s * 0.125f;
}

// ---- bf16x3 MFMA conv, 16x16x32. LDS-BW was the binding limit (85KB LDS
// traffic per block-kx ~ 1000cyc vs 524cyc MFMA -> 176us, MfmaUtil 60%).
// Fix: B goes GLOBAL->VGPR directly (single-use per block; L2/L1-resident via
// XCD-pinned nt slice; uniform base + coalesced 256B segments) -- its traffic
// moves to the idle VMEM pipe. LDS keeps only A (real 3x kx reuse), dbuf'd
// across phases; stage issued after the phase-top barrier hides under the 3
// MFMA clusters. 12 barriers/block (was 72). LDS 33.3KB.
// grid (8 nt, 128 rows, NB batches); nt 0..3 -> logits, 4..7 -> fx_mid.
__global__ __launch_bounds__(256) void conv_mfma_kernel(
    const ushort* __restrict__ xpth, const ushort* __restrict__ xptl,
    const ushort* __restrict__ wth, const ushort* __restrict__ wtl,
    const float* __restrict__ bc, const float* __restrict__ bfx,
    float* __restrict__ lg, float* __restrict__ fxo) {
  // shorts: A0 {Ah@0, Al@4160}, A1 {Ah@8320, Al@12480}. 16640 shorts = 33.3KB.
  __shared__ __align__(16) ushort lds[16640];
  const int bz = blockIdx.z;
  xpth += (size_t)bz * XPT_PLANE;
  xptl += (size_t)bz * XPT_PLANE;
  lg += (size_t)bz * N_ * INNER_;
  fxo += (size_t)bz * N_ * INNER_;
  const int t = threadIdx.x;
  const int lane = t & 63;
  const int wid = t >> 6;
  const int wm = wid & 1, wn = wid >> 1;
  const int nt = blockIdx.x;
  const int y = blockIdx.y;
  const int col = lane & 15, quad = lane >> 4;

  vf4 acc[4][4];
#pragma unroll
  for (int i = 0; i < 4; ++i)
#pragma unroll
    for (int j = 0; j < 4; ++j) acc[i][j] = vf4{0.f, 0.f, 0.f, 0.f};

  // stage A plane for phase p (p = ky*4 + c0i) into buffer `buf` (fully async)
  auto stageA = [&](int p, int buf) {
    const int ky = p >> 2, c0i = p & 3;
    const size_t aoff = ((size_t)(y + ky) * 4 + c0i) * XPT_SLAB;
    const int base = buf * 8320;
    gload16(xpth + aoff + t * 8, lds + base + t * 8);
    gload16(xpth + aoff + 2048 + t * 8, lds + base + 2048 + t * 8);
    gload16(xptl + aoff + t * 8, lds + base + 4160 + t * 8);
    gload16(xptl + aoff + 2048 + t * 8, lds + base + 4160 + 2048 + t * 8);
    if (t < 8) {  // 64-short tails, exec-masked async gload
      gload16(xpth + aoff + 4096 + t * 8, lds + base + 4096 + t * 8);
      gload16(xptl + aoff + 4096 + t * 8, lds + base + 4160 + 4096 + t * 8);
    }
  };

  // per-lane B fragment offset (shorts), loop-invariant
  const int bfrag = (quad * 128 + wn * 64 + col) * 8;

  stageA(0, 0);
  for (int p = 0; p < 12; ++p) {
    __syncthreads();  // A[p] landed; prior phase's reads of buf[(p+1)&1] done
    if (p < 11) stageA(p + 1, (p + 1) & 1);  // flight hides under 3 kx clusters
    const int abase = (p & 1) * 8320;
    const int tap0 = (p >> 2) * 3, c0i = p & 3;
#pragma unroll
    for (int kx = 0; kx < 3; ++kx) {
      const size_t boff = (((size_t)(tap0 + kx) * 8 + nt) * 4 + c0i) * 4096;
      const ushort* __restrict__ bhp = wth + boff + bfrag;
      const ushort* __restrict__ blp = wtl + boff + bfrag;
      sh8 ah[4], al[4], bh[4], bl[4];
#pragma unroll
      for (int j = 0; j < 4; ++j) {
        bh[j] = *reinterpret_cast<const sh8*>(bhp + j * 128);  // j*16 cols * 8
        bl[j] = *reinterpret_cast<const sh8*>(blp + j * 128);
      }
#pragma unroll
      for (int i = 0; i < 4; ++i) {
        const int ard = (quad * 130 + wm * 64 + i * 16 + col + kx) * 8;
        ah[i] = *reinterpret_cast<const sh8*>(lds + abase + ard);
        al[i] = *reinterpret_cast<const sh8*>(lds + abase + 4160 + ard);
      }
      __builtin_amdgcn_s_setprio(1);
#pragma unroll
      for (int i = 0; i < 4; ++i)
#pragma unroll
        for (int j = 0; j < 4; ++j) {
          acc[i][j] = __builtin_amdgcn_mfma_f32_16x16x32_bf16(ah[i], bh[j], acc[i][j], 0, 0, 0);
          acc[i][j] = __builtin_amdgcn_mfma_f32_16x16x32_bf16(ah[i], bl[j], acc[i][j], 0, 0, 0);
          acc[i][j] = __builtin_amdgcn_mfma_f32_16x16x32_bf16(al[i], bh[j], acc[i][j], 0, 0, 0);
        }
      __builtin_amdgcn_s_setprio(0);
    }
  }
  const bool first = (nt < 4);
  float* outp = first ? lg : fxo;
  const float* bb = first ? bc : bfx;
  const int ocbase = (nt & 3) * 128 + wn * 64 + col;
#pragma unroll
  for (int j = 0; j < 4; ++j) {
    const int oc = ocbase + j * 16;
    const float bv = bb[oc];
#pragma unroll
    for (int i = 0; i < 4; ++i) {
#pragma unroll
      for (int r = 0; r < 4; ++r) {
        const int px = wm * 64 + i * 16 + quad * 4 + r;
        outp[((size_t)(y * W_ + px)) * INNER_ + oc] = acc[i][j][r] + bv;
      }
    }
  }
}

__device__ __forceinline__ void fma16(float (&acc)[4][4], const float4 a, const float4 b) {
  acc[0][0] = fmaf(a.x, b.x, acc[0][0]);
  acc[0][1] = fmaf(a.x, b.y, acc[0][1]);
  acc[0][2] = fmaf(a.x, b.z, acc[0][2]);
  acc[0][3] = fmaf(a.x, b.w, acc[0][3]);
  acc[1][0] = fmaf(a.y, b.x, acc[1][0]);
  acc[1][1] = fmaf(a.y, b.y, acc[1][1]);
  acc[1][2] = fmaf(a.y, b.z, acc[1][2]);
  acc[1][3] = fmaf(a.y, b.w, acc[1][3]);
  acc[2][0] = fmaf(a.z, b.x, acc[2][0]);
  acc[2][1] = fmaf(a.z, b.y, acc[2][1]);
  acc[2][2] = fmaf(a.z, b.z, acc[2][2]);
  acc[2][3] = fmaf(a.z, b.w, acc[2][3]);
  acc[3][0] = fmaf(a.w, b.x, acc[3][0]);
  acc[3][1] = fmaf(a.w, b.y, acc[3][1]);
  acc[3][2] = fmaf(a.w, b.z, acc[3][2]);
  acc[3][3] = fmaf(a.w, b.w, acc[3][3]);
}

// softmax (all 256 threads) -> packed hi/lo w in place, NON-ATOMIC per-block
// token/norm partials. grid (512, NB): x = (h, 256-px chunk), y = batch. block 256.
__global__ __launch_bounds__(256) void slice_kernel(float* __restrict__ lg,
                                                    const float* __restrict__ fxg,
                                                    float* __restrict__ tpart,  // [512][4096]
                                                    float* __restrict__ npart) { // [512][64]
  __shared__ __align__(16) float wl[64][68];
  __shared__ __align__(16) float fxl[64][68];
  __shared__ float red[8][64];
  const int bz = blockIdx.y;
  lg += (size_t)bz * N_ * INNER_;
  fxg += (size_t)bz * N_ * INNER_;
  tpart += (size_t)bz * 512 * 4096;
  npart += (size_t)bz * 512 * 64;
  unsigned int* lgp = reinterpret_cast<unsigned int*>(lg);

  const int t = threadIdx.x;
  const int sub = blockIdx.x & 63;
  const int h = blockIdx.x >> 6;
  const int nbase = sub * 256;
  const int tx = t & 15;
  const int ty = t >> 4;
  const int sn = t >> 2;   // softmax row
  const int sq = t & 3;    // softmax quarter (16 g each)
  const int gg2 = t & 63;  // norm column
  const int q2 = t >> 6;   // norm n-quarter

  float acc2[4][4] = {};
  float snrmp = 0.0f;

  for (int s = 0; s < 4; ++s) {
    const int n0 = nbase + s * 64;
    __syncthreads();
    {
      const int cg = t & 15;
      const int nr = t >> 4;
#pragma unroll
      for (int r = 0; r < 4; ++r) {
        const int nn = nr + r * 16;
        const size_t rowoff = ((size_t)(n0 + nn)) * INNER_ + h * DH_ + cg * 4;
        *reinterpret_cast<float4*>(&wl[nn][cg * 4]) =
            *reinterpret_cast<const float4*>(lg + rowoff);
        *reinterpret_cast<float4*>(&fxl[nn][cg * 4]) =
            *reinterpret_cast<const float4*>(fxg + rowoff);
      }
    }
    __syncthreads();
    // softmax over g per row, 4 threads/row
    float m = -3.4e38f;
#pragma unroll
    for (int jj = 0; jj < 16; ++jj) m = fmaxf(m, wl[sn][sq * 16 + jj]);
    red[sq][sn] = m;
    __syncthreads();
    m = fmaxf(fmaxf(red[0][sn], red[1][sn]), fmaxf(red[2][sn], red[3][sn]));
    float ss = 0.0f;
#pragma unroll
    for (int jj = 0; jj < 16; ++jj) {
      const float e = __expf(wl[sn][sq * 16 + jj] - m);
      wl[sn][sq * 16 + jj] = e;
      ss += e;
    }
    red[4 + sq][sn] = ss;
    __syncthreads();
    const float inv = 1.0f / (red[4][sn] + red[5][sn] + red[6][sn] + red[7][sn]);
#pragma unroll
    for (int jj = 0; jj < 16; ++jj) wl[sn][sq * 16 + jj] *= inv;
    __syncthreads();
    // packed write
    {
      const int gg = t & 15;
      const int nr = t >> 4;
#pragma unroll
      for (int r = 0; r < 4; ++r) {
        const int nn = nr + r * 16;
        uint4 pk;
        unsigned int* pp = reinterpret_cast<unsigned int*>(&pk);
#pragma unroll
        for (int j = 0; j < 4; ++j) {
          ushort hh, ll;
          split_bf16(wl[nn][gg * 4 + j], hh, ll);
          pp[j] = ((unsigned int)hh << 16) | (unsigned int)ll;
        }
        *reinterpret_cast<uint4*>(lgp + ((size_t)(n0 + nn)) * INNER_ + h * DH_ + gg * 4) = pk;
      }
    }
    // norm partial (distributed)
#pragma unroll
    for (int nn = 0; nn < 16; ++nn) snrmp += wl[q2 * 16 + nn][gg2];
    // token GEMM partial
#pragma unroll
    for (int kk = 0; kk < 64; ++kk) {
      const float4 a4 = *reinterpret_cast<const float4*>(&wl[kk][ty * 4]);
      const float4 b4 = *reinterpret_cast<const float4*>(&fxl[kk][tx * 4]);
      fma16(acc2, a4, b4);
    }
  }
  __syncthreads();
  red[q2][gg2] = snrmp;
  // flush partials (non-atomic, coalesced float4)
  float* tp = tpart + (size_t)blockIdx.x * 4096;
#pragma unroll
  for (int i = 0; i < 4; ++i) {
    float4 v;
    v.x = acc2[i][0];
    v.y = acc2[i][1];
    v.z = acc2[i][2];
    v.w = acc2[i][3];
    *reinterpret_cast<float4*>(tp + (ty * 4 + i) * 64 + tx * 4) = v;
  }
  __syncthreads();
  if (t < 64)
    npart[(size_t)blockIdx.x * 64 + t] = red[0][t] + red[1][t] + red[2][t] + red[3][t];
}

// Sum 64 chunk partials -> tok [8][4096], nrm [8][64]. grid (129, NB), block 256.
__global__ __launch_bounds__(256) void reduce_kernel(const float* __restrict__ tpart,
                                                     const float* __restrict__ npart,
                                                     float* __restrict__ tok,
                                                     float* __restrict__ nrm) {
  const int bz = blockIdx.y;
  tpart += (size_t)bz * 512 * 4096;
  npart += (size_t)bz * 512 * 64;
  tok += (size_t)bz * (HEADS_ * G_ * DH_);
  nrm += (size_t)bz * (HEADS_ * G_);
  if (blockIdx.x < 128) {
    const int idx = blockIdx.x * 256 + threadIdx.x;  // 32768
    const int h = idx >> 12, e = idx & 4095;
    float s = 0.f;
    for (int cb = 0; cb < 64; ++cb)
      s += tpart[(((size_t)(h * 64 + cb)) << 12) + e];
    tok[idx] = s;
  } else {
    for (int o = threadIdx.x; o < 512; o += 256) {
      const int h = o >> 6, g = o & 63;
      float s = 0.f;
      for (int cb = 0; cb < 64; ++cb) s += npart[(size_t)(h * 64 + cb) * 64 + g];
      nrm[o] = s;
    }
  }
}

// Fused qkv+attn+outmat per head. grid (8, NB), block 256.
__global__ __launch_bounds__(256) void head_kernel(const float* __restrict__ tok,
                                                   const float* __restrict__ nrm,
                                                   const float* __restrict__ mqk,
                                                   const float* __restrict__ Wv,
                                                   const float* __restrict__ Wo,
                                                   ushort* __restrict__ mht,
                                                   ushort* __restrict__ mlt) {
  __shared__ float ST[64 * 65];
  __shared__ float YL[64 * 64];
  __shared__ float VL[64 * 64];
  __shared__ float red[8][64];
  const int bz = blockIdx.y;
  tok += (size_t)bz * (HEADS_ * G_ * DH_);
  nrm += (size_t)bz * (HEADS_ * G_);
  mht += (size_t)bz * (INNER_ * DIM_);
  mlt += (size_t)bz * (INNER_ * DIM_);
  const int t = threadIdx.x;
  const int h = blockIdx.x;

  for (int e = t; e < 4096; e += 256) {
    const int g = e >> 6, c = e & 63;
    ST[g * 65 + c] = tok[(size_t)h * 4096 + e] / (nrm[h * 64 + g] + 1e-5f);
  }
  __syncthreads();
  for (int e = t; e < 4096; e += 256) {
    const int k = e >> 6, c = e & 63;
    float sy = 0.f, sv = 0.f;
    const float* mrow = mqk + c * 64;
    const float* wrow = Wv + c * 64;
#pragma unroll
    for (int c2 = 0; c2 < 64; ++c2) {
      const float st2 = ST[k * 65 + c2];
      sy = fmaf(mrow[c2], st2, sy);
      sv = fmaf(wrow[c2], st2, sv);
    }
    YL[k * 64 + c] = sy;
    VL[k * 64 + c] = sv;
  }
  __syncthreads();
  const int g = t & 63, kp = t >> 6;
  float z[16];
#pragma unroll
  for (int j = 0; j < 16; ++j) z[j] = 0.f;
  for (int c = 0; c < 64; ++c) {
    const float sg = ST[g * 65 + c];
#pragma unroll
    for (int j = 0; j < 16; ++j) z[j] = fmaf(sg, YL[(kp * 16 + j) * 64 + c], z[j]);
  }
  float m = z[0];
#pragma unroll
  for (int j = 1; j < 16; ++j) m = fmaxf(m, z[j]);
  red[kp][g] = m;
  __syncthreads();
  m = fmaxf(fmaxf(red[0][g], red[1][g]), fmaxf(red[2][g], red[3][g]));
  float ssum = 0.f;
#pragma unroll
  for (int j = 0; j < 16; ++j) {
    z[j] = __expf(z[j] - m);
    ssum += z[j];
  }
  red[4 + kp][g] = ssum;
  __syncthreads();
  ssum = red[4][g] + red[5][g] + red[6][g] + red[7][g];
  const float inv = 1.f / ssum;
#pragma unroll
  for (int j = 0; j < 16; ++j) ST[(kp * 16 + j) * 65 + g] = z[j] * inv;
  __syncthreads();
  for (int e = t; e < 4096; e += 256) {
    const int gg = e >> 6, d = e & 63;
    float s = 0.f;
#pragma unroll
    for (int k = 0; k < 64; ++k) s = fmaf(ST[k * 65 + gg], VL[k * 64 + d], s);
    YL[gg * 64 + d] = s;
  }
  __syncthreads();
  for (int e = t; e < 8192; e += 256) {
    const int o = e & 127, gg = e >> 7;
    float s = 0.f;
    const float* wrow = Wo + (size_t)o * INNER_ + h * 64;
#pragma unroll
    for (int d = 0; d < 64; ++d) s = fmaf(YL[gg * 64 + d], wrow[d], s);
    ushort hh, ll;
    split_bf16(s, hh, ll);
    const int hg = h * 64 + gg;
    const int kg2 = hg >> 3, kr = hg & 7;
    mht[((size_t)kg2 * 128 + o) * 8 + kr] = hh;
    mlt[((size_t)kg2 * 128 + o) * 8 + kr] = ll;
  }
}

// out[n][o] = sum_k w[n][k]*Mcat[k][o] + bo[o]; bf16x3 MFMA. grid (256, NB).
__global__ __launch_bounds__(256) void fused_out_kernel(
    const unsigned int* __restrict__ wp,
    const ushort* __restrict__ mht,
    const ushort* __restrict__ mlt,
    const float* __restrict__ bo,
    float* __restrict__ out) {
  __shared__ __align__(16) ushort lds[24576];
  const int bz = blockIdx.y;
  wp += (size_t)bz * N_ * INNER_;
  mht += (size_t)bz * (INNER_ * DIM_);
  mlt += (size_t)bz * (INNER_ * DIM_);
  out += (size_t)bz * N_ * DIM_;
  const int t = threadIdx.x;
  const int lane = t & 63;
  const int wid = t >> 6;
  const int wm = wid & 1, wn = wid >> 1;
  const int col = lane & 15, quad = lane >> 4;
  const int n0 = blockIdx.x * 64;

  vf4 acc[2][4];
#pragma unroll
  for (int m = 0; m < 2; ++m)
#pragma unroll
    for (int n = 0; n < 4; ++n) acc[m][n] = vf4{0.f, 0.f, 0.f, 0.f};

  for (int kc = 0; kc < 8; ++kc) {
    __syncthreads();
#pragma unroll
    for (int r = 0; r < 2; ++r) {
      const int row = r * 256 + t;
      const int pix = row >> 3, kg2 = row & 7;
      const unsigned int* gp = wp + (size_t)(n0 + pix) * INNER_ + kc * 64 + kg2 * 8;
      const uint4 p0 = *reinterpret_cast<const uint4*>(gp);
      const uint4 p1 = *reinterpret_cast<const uint4*>(gp + 4);
      unsigned int u[8] = {p0.x, p0.y, p0.z, p0.w, p1.x, p1.y, p1.z, p1.w};
      sh8 hv, lv;
#pragma unroll
      for (int j = 0; j < 8; ++j) {
        hv[j] = (short)(u[j] >> 16);
        lv[j] = (short)(u[j] & 0xffff);
      }
      const int drow = pix * 8 + (kg2 ^ (pix & 7));
      *reinterpret_cast<sh8*>(lds + drow * 8) = hv;
      *reinterpret_cast<sh8*>(lds + 4096 + drow * 8) = lv;
    }
#pragma unroll
    for (int r = 0; r < 4; ++r) {
      gload16(mht + (size_t)kc * 8192 + ((size_t)r * 256 + t) * 8, lds + 8192 + r * 2048 + t * 8);
      gload16(mlt + (size_t)kc * 8192 + ((size_t)r * 256 + t) * 8, lds + 16384 + r * 2048 + t * 8);
    }
    __syncthreads();
#pragma unroll
    for (int kk = 0; kk < 2; ++kk) {
      const int kg2 = kk * 4 + quad;
      sh8 ah[2], al[2], bh[4], bl[4];
#pragma unroll
      for (int m = 0; m < 2; ++m) {
        const int pix = wm * 32 + m * 16 + col;
        const int drow = pix * 8 + (kg2 ^ (pix & 7));
        ah[m] = *reinterpret_cast<const sh8*>(lds + drow * 8);
        al[m] = *reinterpret_cast<const sh8*>(lds + 4096 + drow * 8);
      }
#pragma unroll
      for (int n = 0; n < 4; ++n) {
        const int o = wn * 64 + n * 16 + col;
        bh[n] = *reinterpret_cast<const sh8*>(lds + 8192 + ((size_t)kg2 * 128 + o) * 8);
        bl[n] = *reinterpret_cast<const sh8*>(lds + 16384 + ((size_t)kg2 * 128 + o) * 8);
      }
      __builtin_amdgcn_s_setprio(1);
#pragma unroll
      for (int m = 0; m < 2; ++m)
#pragma unroll
        for (int n = 0; n < 4; ++n) {
          acc[m][n] = __builtin_amdgcn_mfma_f32_16x16x32_bf16(ah[m], bh[n], acc[m][n], 0, 0, 0);
          acc[m][n] = __builtin_amdgcn_mfma_f32_16x16x32_bf16(ah[m], bl[n], acc[m][n], 0, 0, 0);
          acc[m][n] = __builtin_amdgcn_mfma_f32_16x16x32_bf16(al[m], bh[n], acc[m][n], 0, 0, 0);
        }
      __builtin_amdgcn_s_setprio(0);
    }
  }
#pragma unroll
  for (int n = 0; n < 4; ++n) {
    const int o = wn * 64 + n * 16 + col;
    const float bv = bo[o];
#pragma unroll
    for (int m = 0; m < 2; ++m) {
#pragma unroll
      for (int r = 0; r < 4; ++r) {
        const int pix = wm * 32 + m * 16 + quad * 4 + r;
        out[(size_t)(n0 + pix) * DIM_ + o] = acc[m][n][r] + bv;
      }
    }
  }
}

extern "C" void kernel_launch(void* const* d_in, const int* in_sizes, int n_in,
                              void* d_out, int out_size, void* d_ws, size_t ws_size,
                              hipStream_t stream) {
  const float* x    = (const float*)d_in[0];
  const float* temp = (const float*)d_in[1];
  const float* Wx   = (const float*)d_in[2];
  const float* bx   = (const float*)d_in[3];
  const float* Wfx  = (const float*)d_in[4];
  const float* bfx  = (const float*)d_in[5];
  const float* Ws   = (const float*)d_in[6];
  const float* bs   = (const float*)d_in[7];
  const float* Wq   = (const float*)d_in[8];
  const float* Wk   = (const float*)d_in[9];
  const float* Wv   = (const float*)d_in[10];
  const float* Wo   = (const float*)d_in[11];
  const float* bo   = (const float*)d_in[12];
  float* out = (float*)d_out;

  // Workspace need as a function of batches-per-launch nb.
  auto need = [](int nb) -> size_t {
    size_t s = 0;
    s += 2 * (size_t)WT_PLANE * 2;                 // WTH/WTL
    s += 2 * (size_t)nb * XPT_PLANE * 2;           // XPTH/XPTL
    s += 2 * (size_t)nb * N_ * INNER_ * 4;         // LG/FXO
    s += (size_t)B_ * HEADS_ * G_ * DH_ * 4;       // TOK (always full B_)
    s += (size_t)B_ * HEADS_ * G_ * 4;             // NRM
    s += (size_t)DH_ * DH_ * 4;                    // MQK
    s += (size_t)INNER_ * 4;                       // BC
    s += 2 * (size_t)nb * INNER_ * DIM_ * 2;       // MHT/MLT
    s += (size_t)nb * 512 * 4096 * 4;              // TP
    s += (size_t)nb * 512 * 64 * 4;                // NP
    return s;
  };
  int nb = 1;
  if (ws_size >= need(4)) nb = 4;
  else if (ws_size >= need(2)) nb = 2;

  char* p = (char*)d_ws;
  ushort* WTH = (ushort*)p; p += (size_t)WT_PLANE * 2;
  ushort* WTL = (ushort*)p; p += (size_t)WT_PLANE * 2;
  ushort* XPTH = (ushort*)p; p += (size_t)nb * XPT_PLANE * 2;
  ushort* XPTL = (ushort*)p; p += (size_t)nb * XPT_PLANE * 2;
  float* LG  = (float*)p; p += (size_t)nb * N_ * INNER_ * 4;   // logits -> packed w
  float* FXO = (float*)p; p += (size_t)nb * N_ * INNER_ * 4;   // fx_mid
  float* TOK = (float*)p; p += (size_t)B_ * HEADS_ * G_ * DH_ * 4;
  float* NRM = (float*)p; p += (size_t)B_ * HEADS_ * G_ * 4;
  float* MQK = (float*)p; p += (size_t)DH_ * DH_ * 4;
  float* BC  = (float*)p; p += (size_t)INNER_ * 4;
  ushort* MHT = (ushort*)p; p += (size_t)nb * INNER_ * DIM_ * 2;
  ushort* MLT = (ushort*)p; p += (size_t)nb * INNER_ * DIM_ * 2;
  float* TP  = (float*)p; p += (size_t)nb * 512 * 4096 * 4;    // token partials
  float* NP  = (float*)p; p += (size_t)nb * 512 * 64 * 4;      // norm partials

  wfx_kernel<<<2304, 256, 0, stream>>>(Wfx, WTH, WTL);
  wcomp_kernel<<<dim3(9, 8), 256, 0, stream>>>(Wx, Ws, bx, bs, temp, WTH, WTL, BC);
  mqk_kernel<<<16, 256, 0, stream>>>(Wq, Wk, MQK);

  for (int b0 = 0; b0 < B_; b0 += nb) {
    const float* xb = x + (size_t)b0 * N_ * DIM_;
    float* outb = out + (size_t)b0 * N_ * DIM_;
    float* tokb = TOK + (size_t)b0 * HEADS_ * G_ * DH_;
    float* nrmb = NRM + (size_t)b0 * HEADS_ * G_;

    pad_tile_kernel<<<dim3(8450, nb), 256, 0, stream>>>(xb, XPTH, XPTL);
    conv_mfma_kernel<<<dim3(8, 128, nb), 256, 0, stream>>>(XPTH, XPTL, WTH, WTL, BC, bfx, LG, FXO);
    slice_kernel<<<dim3(512, nb), 256, 0, stream>>>(LG, FXO, TP, NP);
    reduce_kernel<<<dim3(129, nb), 256, 0, stream>>>(TP, NP, tokb, nrmb);
    head_kernel<<<dim3(8, nb), 256, 0, stream>>>(tokb, nrmb, MQK, Wv, Wo, MHT, MLT);
    fused_out_kernel<<<dim3(256, nb), 256, 0, stream>>>((const unsigned int*)LG, MHT, MLT, bo, outb);
  }
}

// Round 11
// 740.167 us; speedup vs baseline: 1.0396x; 1.0396x over previous
//
#include <hip/hip_runtime.h>
#include <hip/hip_bf16.h>
#include <math.h>

#define B_ 4
#define H_ 128
#define W_ 128
#define DIM_ 128
#define HEADS_ 8
#define DH_ 64
#define G_ 64
#define INNER_ 512
#define N_ 16384

typedef __attribute__((ext_vector_type(8))) short sh8;
typedef __attribute__((ext_vector_type(4))) float vf4;

// XPT tiled input layout (per plane): [row 0..129][c0 0..3][tile][8]
//   tile = kg*131 + px  (kg = channel-group of 8 within 32-chunk, px = padded col)
// px stride 131 (ODD, was 130): the four 16-lane quarters of the conv A-read
// land at 131-unit steps -> bank-row de-aliased.
// (130 cost exactly 4 conflict-cycles per ds_read_b128: measured
// 9,437,184 = 4 x 2,359,296 reads, invariant across rounds 3-9.)
// slab per (row,c0) = 524*8 = 4192 shorts.  plane = 130*4*4192 = 2179840 shorts.
#define XPT_SLAB 4192
#define XPT_PLANE 2179840
// WT tiled weight layout (per plane): [tap 0..8][nt 0..7][c0 0..3][tile 0..511][8]
//   tile = kg*128 + oc(0..127), oc global = nt*128+oc.
#define WT_PLANE 1179648

__device__ __forceinline__ void gload16(const void* g, void* l) {
  __builtin_amdgcn_global_load_lds((const __attribute__((address_space(1))) void*)g,
                                   (__attribute__((address_space(3))) void*)l, 16, 0, 0);
}

__device__ __forceinline__ void split_bf16(float v, ushort& h, ushort& l) {
  __hip_bfloat16 hb = __float2bfloat16(v);
  float hf = __bfloat162float(hb);
  __hip_bfloat16 lb = __float2bfloat16(v - hf);
  h = *reinterpret_cast<ushort*>(&hb);
  l = *reinterpret_cast<ushort*>(&lb);
}

// ---- prep: pad+split batch-slice of x directly into XPT tiled hi/lo layout ----
// grid (8515, NB): blockIdx.y = batch within this launch. 8515*256 = 2179840.
__global__ __launch_bounds__(256) void pad_tile_kernel(const float* __restrict__ x,
                                                       ushort* __restrict__ xpth,
                                                       ushort* __restrict__ xptl) {
  const int bz = blockIdx.y;
  x += (size_t)bz * N_ * DIM_;
  xpth += (size_t)bz * XPT_PLANE;
  xptl += (size_t)bz * XPT_PLANE;
  const int idx = blockIdx.x * 256 + threadIdx.x;
  const int row = idx / (4 * XPT_SLAB);
  const int rem = idx % (4 * XPT_SLAB);
  const int c0i = rem / XPT_SLAB;
  const int t2 = rem % XPT_SLAB;
  const int tile = t2 >> 3, j = t2 & 7;
  const int kg = tile / 131, px = tile % 131;
  const int c = c0i * 32 + kg * 8 + j;
  float v = 0.0f;
  if (row >= 1 && row <= H_ && px >= 1 && px <= W_)
    v = x[((size_t)(row - 1) * W_ + (px - 1)) * DIM_ + c];
  ushort hh, ll;
  split_bf16(v, hh, ll);
  xpth[idx] = hh;
  xptl[idx] = ll;
}

// ---- prep: fx-branch weights into WT tiled layout (nt 4..7) ----
__global__ __launch_bounds__(256) void wfx_kernel(const float* __restrict__ Wfx,
                                                  ushort* __restrict__ wth,
                                                  ushort* __restrict__ wtl) {
  int idx = blockIdx.x * 256 + threadIdx.x;
  if (idx >= 9 * 512 * DIM_) return;
  const int c = idx & 127;
  const int ocf = (idx >> 7) & 511;
  const int tap = idx >> 16;
  float v = Wfx[((size_t)ocf * DIM_ + c) * 9 + tap];
  ushort hh, ll;
  split_bf16(v, hh, ll);
  const int nt = 4 + (ocf >> 7), oci = ocf & 127;
  const int c0i = c >> 5, kg = (c >> 3) & 3, j = c & 7;
  const size_t o = (((size_t)tap * 8 + nt) * 4 + c0i) * 4096 + ((size_t)kg * 128 + oci) * 8 + j;
  wth[o] = hh;
  wtl[o] = ll;
}

// ---- prep: composed x-branch weights (Ws/temp folded), WT tiled (nt 0..3) + bias bc ----
__global__ __launch_bounds__(256) void wcomp_kernel(const float* __restrict__ Wx,
                                                    const float* __restrict__ Ws,
                                                    const float* __restrict__ bx,
                                                    const float* __restrict__ bs,
                                                    const float* __restrict__ temperature,
                                                    ushort* __restrict__ wth,
                                                    ushort* __restrict__ wtl,
                                                    float* __restrict__ bc) {
  __shared__ float WxL[64][128];
  __shared__ float WsL[64][64];
  const int t = threadIdx.x;
  const int tap = blockIdx.x, h = blockIdx.y;
  for (int e = t; e < 8192; e += 256) {
    const int c2 = e >> 7, c = e & 127;
    WxL[c2][c] = Wx[((size_t)(h * 64 + c2) * DIM_ + c) * 9 + tap];
  }
  for (int e = t; e < 4096; e += 256) WsL[e >> 6][e & 63] = Ws[e];
  float tmp = fminf(fmaxf(temperature[h], 0.1f), 5.0f);
  const float invt = 1.0f / tmp;
  __syncthreads();
  for (int e = t; e < 8192; e += 256) {
    const int gg = e >> 7, c = e & 127;
    float s = 0.f;
#pragma unroll
    for (int c2 = 0; c2 < 64; ++c2) s = fmaf(WsL[gg][c2], WxL[c2][c], s);
    s *= invt;
    ushort hh, ll;
    split_bf16(s, hh, ll);
    const int ocp = h * 64 + gg;
    const int nt = ocp >> 7, oci = ocp & 127;
    const int c0i = c >> 5, kg = (c >> 3) & 3, j = c & 7;
    const size_t o = (((size_t)tap * 8 + nt) * 4 + c0i) * 4096 + ((size_t)kg * 128 + oci) * 8 + j;
    wth[o] = hh;
    wtl[o] = ll;
  }
  if (tap == 0 && t < 64) {
    float s = 0.f;
#pragma unroll
    for (int c2 = 0; c2 < 64; ++c2) s = fmaf(Ws[t * 64 + c2], bx[h * 64 + c2], s);
    bc[h * 64 + t] = (s + bs[t]) * invt;
  }
}

// ---- prep: Mqk[c][c'] = scale * sum_d Wq[d][c]*Wk[d][c'] ----
__global__ __launch_bounds__(256) void mqk_kernel(const float* __restrict__ Wq,
                                                  const float* __restrict__ Wk,
                                                  float* __restrict__ mqk) {
  const int idx = blockIdx.x * 256 + threadIdx.x;  // 4096
  const int c = idx >> 6, c2 = idx & 63;
  float s = 0.f;
#pragma unroll
  for (int d = 0; d < 64; ++d) s = fmaf(Wq[d * 64 + c], Wk[d * 64 + c2], s);
  mqk[idx] = s * 0.125f;
}

// ---- bf16x3 MFMA conv, 16x16x32. B GLOBAL->VGPR (r9), A dbuf in LDS with
// stride-131 px rows (bank de-alias; was 4 conflict-cyc per A ds_read_b128).
// grid (8 nt, 128 rows, NB batches); nt 0..3 -> logits, 4..7 -> fx_mid.
__global__ __launch_bounds__(256) void conv_mfma_kernel(
    const ushort* __restrict__ xpth, const ushort* __restrict__ xptl,
    const ushort* __restrict__ wth, const ushort* __restrict__ wtl,
    const float* __restrict__ bc, const float* __restrict__ bfx,
    float* __restrict__ lg, float* __restrict__ fxo) {
  // shorts: A0 {Ah@0, Al@4192}, A1 {Ah@8384, Al@12576}. 16768 shorts = 33.5KB.
  __shared__ __align__(16) ushort lds[16768];
  const int bz = blockIdx.z;
  xpth += (size_t)bz * XPT_PLANE;
  xptl += (size_t)bz * XPT_PLANE;
  lg += (size_t)bz * N_ * INNER_;
  fxo += (size_t)bz * N_ * INNER_;
  const int t = threadIdx.x;
  const int lane = t & 63;
  const int wid = t >> 6;
  const int wm = wid & 1, wn = wid >> 1;
  const int nt = blockIdx.x;
  const int y = blockIdx.y;
  const int col = lane & 15, quad = lane >> 4;

  vf4 acc[4][4];
#pragma unroll
  for (int i = 0; i < 4; ++i)
#pragma unroll
    for (int j = 0; j < 4; ++j) acc[i][j] = vf4{0.f, 0.f, 0.f, 0.f};

  // stage A plane for phase p (p = ky*4 + c0i) into buffer `buf` (fully async)
  auto stageA = [&](int p, int buf) {
    const int ky = p >> 2, c0i = p & 3;
    const size_t aoff = ((size_t)(y + ky) * 4 + c0i) * XPT_SLAB;
    const int base = buf * 8384;
    gload16(xpth + aoff + t * 8, lds + base + t * 8);
    gload16(xpth + aoff + 2048 + t * 8, lds + base + 2048 + t * 8);
    gload16(xptl + aoff + t * 8, lds + base + 4192 + t * 8);
    gload16(xptl + aoff + 2048 + t * 8, lds + base + 4192 + 2048 + t * 8);
    if (t < 12) {  // 96-short tails, exec-masked async gload
      gload16(xpth + aoff + 4096 + t * 8, lds + base + 4096 + t * 8);
      gload16(xptl + aoff + 4096 + t * 8, lds + base + 4192 + 4096 + t * 8);
    }
  };

  // per-lane B fragment offset (shorts), loop-invariant
  const int bfrag = (quad * 128 + wn * 64 + col) * 8;

  stageA(0, 0);
  for (int p = 0; p < 12; ++p) {
    __syncthreads();  // A[p] landed; prior phase's reads of buf[(p+1)&1] done
    if (p < 11) stageA(p + 1, (p + 1) & 1);  // flight hides under 3 kx clusters
    const int abase = (p & 1) * 8384;
    const int tap0 = (p >> 2) * 3, c0i = p & 3;
#pragma unroll
    for (int kx = 0; kx < 3; ++kx) {
      const size_t boff = (((size_t)(tap0 + kx) * 8 + nt) * 4 + c0i) * 4096;
      const ushort* __restrict__ bhp = wth + boff + bfrag;
      const ushort* __restrict__ blp = wtl + boff + bfrag;
      sh8 ah[4], al[4], bh[4], bl[4];
#pragma unroll
      for (int j = 0; j < 4; ++j) {
        bh[j] = *reinterpret_cast<const sh8*>(bhp + j * 128);  // j*16 cols * 8
        bl[j] = *reinterpret_cast<const sh8*>(blp + j * 128);
      }
#pragma unroll
      for (int i = 0; i < 4; ++i) {
        const int ard = (quad * 131 + wm * 64 + i * 16 + col + kx) * 8;
        ah[i] = *reinterpret_cast<const sh8*>(lds + abase + ard);
        al[i] = *reinterpret_cast<const sh8*>(lds + abase + 4192 + ard);
      }
      __builtin_amdgcn_s_setprio(1);
#pragma unroll
      for (int i = 0; i < 4; ++i)
#pragma unroll
        for (int j = 0; j < 4; ++j) {
          acc[i][j] = __builtin_amdgcn_mfma_f32_16x16x32_bf16(ah[i], bh[j], acc[i][j], 0, 0, 0);
          acc[i][j] = __builtin_amdgcn_mfma_f32_16x16x32_bf16(ah[i], bl[j], acc[i][j], 0, 0, 0);
          acc[i][j] = __builtin_amdgcn_mfma_f32_16x16x32_bf16(al[i], bh[j], acc[i][j], 0, 0, 0);
        }
      __builtin_amdgcn_s_setprio(0);
    }
  }
  const bool first = (nt < 4);
  float* outp = first ? lg : fxo;
  const float* bb = first ? bc : bfx;
  const int ocbase = (nt & 3) * 128 + wn * 64 + col;
#pragma unroll
  for (int j = 0; j < 4; ++j) {
    const int oc = ocbase + j * 16;
    const float bv = bb[oc];
#pragma unroll
    for (int i = 0; i < 4; ++i) {
#pragma unroll
      for (int r = 0; r < 4; ++r) {
        const int px = wm * 64 + i * 16 + quad * 4 + r;
        outp[((size_t)(y * W_ + px)) * INNER_ + oc] = acc[i][j][r] + bv;
      }
    }
  }
}

__device__ __forceinline__ void fma16(float (&acc)[4][4], const float4 a, const float4 b) {
  acc[0][0] = fmaf(a.x, b.x, acc[0][0]);
  acc[0][1] = fmaf(a.x, b.y, acc[0][1]);
  acc[0][2] = fmaf(a.x, b.z, acc[0][2]);
  acc[0][3] = fmaf(a.x, b.w, acc[0][3]);
  acc[1][0] = fmaf(a.y, b.x, acc[1][0]);
  acc[1][1] = fmaf(a.y, b.y, acc[1][1]);
  acc[1][2] = fmaf(a.y, b.z, acc[1][2]);
  acc[1][3] = fmaf(a.y, b.w, acc[1][3]);
  acc[2][0] = fmaf(a.z, b.x, acc[2][0]);
  acc[2][1] = fmaf(a.z, b.y, acc[2][1]);
  acc[2][2] = fmaf(a.z, b.z, acc[2][2]);
  acc[2][3] = fmaf(a.z, b.w, acc[2][3]);
  acc[3][0] = fmaf(a.w, b.x, acc[3][0]);
  acc[3][1] = fmaf(a.w, b.y, acc[3][1]);
  acc[3][2] = fmaf(a.w, b.z, acc[3][2]);
  acc[3][3] = fmaf(a.w, b.w, acc[3][3]);
}

// softmax (all 256 threads) -> packed hi/lo w in place, NON-ATOMIC per-block
// token/norm partials. grid (512, NB): x = (h, 256-px chunk), y = batch. block 256.
__global__ __launch_bounds__(256) void slice_kernel(float* __restrict__ lg,
                                                    const float* __restrict__ fxg,
                                                    float* __restrict__ tpart,  // [512][4096]
                                                    float* __restrict__ npart) { // [512][64]
  __shared__ __align__(16) float wl[64][68];
  __shared__ __align__(16) float fxl[64][68];
  __shared__ float red[8][64];
  const int bz = blockIdx.y;
  lg += (size_t)bz * N_ * INNER_;
  fxg += (size_t)bz * N_ * INNER_;
  tpart += (size_t)bz * 512 * 4096;
  npart += (size_t)bz * 512 * 64;
  unsigned int* lgp = reinterpret_cast<unsigned int*>(lg);

  const int t = threadIdx.x;
  const int sub = blockIdx.x & 63;
  const int h = blockIdx.x >> 6;
  const int nbase = sub * 256;
  const int tx = t & 15;
  const int ty = t >> 4;
  const int sn = t >> 2;   // softmax row
  const int sq = t & 3;    // softmax quarter (16 g each)
  const int gg2 = t & 63;  // norm column
  const int q2 = t >> 6;   // norm n-quarter

  float acc2[4][4] = {};
  float snrmp = 0.0f;

  for (int s = 0; s < 4; ++s) {
    const int n0 = nbase + s * 64;
    __syncthreads();
    {
      const int cg = t & 15;
      const int nr = t >> 4;
#pragma unroll
      for (int r = 0; r < 4; ++r) {
        const int nn = nr + r * 16;
        const size_t rowoff = ((size_t)(n0 + nn)) * INNER_ + h * DH_ + cg * 4;
        *reinterpret_cast<float4*>(&wl[nn][cg * 4]) =
            *reinterpret_cast<const float4*>(lg + rowoff);
        *reinterpret_cast<float4*>(&fxl[nn][cg * 4]) =
            *reinterpret_cast<const float4*>(fxg + rowoff);
      }
    }
    __syncthreads();
    // softmax over g per row, 4 threads/row
    float m = -3.4e38f;
#pragma unroll
    for (int jj = 0; jj < 16; ++jj) m = fmaxf(m, wl[sn][sq * 16 + jj]);
    red[sq][sn] = m;
    __syncthreads();
    m = fmaxf(fmaxf(red[0][sn], red[1][sn]), fmaxf(red[2][sn], red[3][sn]));
    float ss = 0.0f;
#pragma unroll
    for (int jj = 0; jj < 16; ++jj) {
      const float e = __expf(wl[sn][sq * 16 + jj] - m);
      wl[sn][sq * 16 + jj] = e;
      ss += e;
    }
    red[4 + sq][sn] = ss;
    __syncthreads();
    const float inv = 1.0f / (red[4][sn] + red[5][sn] + red[6][sn] + red[7][sn]);
#pragma unroll
    for (int jj = 0; jj < 16; ++jj) wl[sn][sq * 16 + jj] *= inv;
    __syncthreads();
    // packed write
    {
      const int gg = t & 15;
      const int nr = t >> 4;
#pragma unroll
      for (int r = 0; r < 4; ++r) {
        const int nn = nr + r * 16;
        uint4 pk;
        unsigned int* pp = reinterpret_cast<unsigned int*>(&pk);
#pragma unroll
        for (int j = 0; j < 4; ++j) {
          ushort hh, ll;
          split_bf16(wl[nn][gg * 4 + j], hh, ll);
          pp[j] = ((unsigned int)hh << 16) | (unsigned int)ll;
        }
        *reinterpret_cast<uint4*>(lgp + ((size_t)(n0 + nn)) * INNER_ + h * DH_ + gg * 4) = pk;
      }
    }
    // norm partial (distributed)
#pragma unroll
    for (int nn = 0; nn < 16; ++nn) snrmp += wl[q2 * 16 + nn][gg2];
    // token GEMM partial
#pragma unroll
    for (int kk = 0; kk < 64; ++kk) {
      const float4 a4 = *reinterpret_cast<const float4*>(&wl[kk][ty * 4]);
      const float4 b4 = *reinterpret_cast<const float4*>(&fxl[kk][tx * 4]);
      fma16(acc2, a4, b4);
    }
  }
  __syncthreads();
  red[q2][gg2] = snrmp;
  // flush partials (non-atomic, coalesced float4)
  float* tp = tpart + (size_t)blockIdx.x * 4096;
#pragma unroll
  for (int i = 0; i < 4; ++i) {
    float4 v;
    v.x = acc2[i][0];
    v.y = acc2[i][1];
    v.z = acc2[i][2];
    v.w = acc2[i][3];
    *reinterpret_cast<float4*>(tp + (ty * 4 + i) * 64 + tx * 4) = v;
  }
  __syncthreads();
  if (t < 64)
    npart[(size_t)blockIdx.x * 64 + t] = red[0][t] + red[1][t] + red[2][t] + red[3][t];
}

// Sum 64 chunk partials -> tok [8][4096], nrm [8][64]. grid (129, NB), block 256.
__global__ __launch_bounds__(256) void reduce_kernel(const float* __restrict__ tpart,
                                                     const float* __restrict__ npart,
                                                     float* __restrict__ tok,
                                                     float* __restrict__ nrm) {
  const int bz = blockIdx.y;
  tpart += (size_t)bz * 512 * 4096;
  npart += (size_t)bz * 512 * 64;
  tok += (size_t)bz * (HEADS_ * G_ * DH_);
  nrm += (size_t)bz * (HEADS_ * G_);
  if (blockIdx.x < 128) {
    const int idx = blockIdx.x * 256 + threadIdx.x;  // 32768
    const int h = idx >> 12, e = idx & 4095;
    float s = 0.f;
    for (int cb = 0; cb < 64; ++cb)
      s += tpart[(((size_t)(h * 64 + cb)) << 12) + e];
    tok[idx] = s;
  } else {
    for (int o = threadIdx.x; o < 512; o += 256) {
      const int h = o >> 6, g = o & 63;
      float s = 0.f;
      for (int cb = 0; cb < 64; ++cb) s += npart[(size_t)(h * 64 + cb) * 64 + g];
      nrm[o] = s;
    }
  }
}

// Fused qkv+attn+outmat per head. grid (8, NB), block 256.
__global__ __launch_bounds__(256) void head_kernel(const float* __restrict__ tok,
                                                   const float* __restrict__ nrm,
                                                   const float* __restrict__ mqk,
                                                   const float* __restrict__ Wv,
                                                   const float* __restrict__ Wo,
                                                   ushort* __restrict__ mht,
                                                   ushort* __restrict__ mlt) {
  __shared__ float ST[64 * 65];
  __shared__ float YL[64 * 64];
  __shared__ float VL[64 * 64];
  __shared__ float red[8][64];
  const int bz = blockIdx.y;
  tok += (size_t)bz * (HEADS_ * G_ * DH_);
  nrm += (size_t)bz * (HEADS_ * G_);
  mht += (size_t)bz * (INNER_ * DIM_);
  mlt += (size_t)bz * (INNER_ * DIM_);
  const int t = threadIdx.x;
  const int h = blockIdx.x;

  for (int e = t; e < 4096; e += 256) {
    const int g = e >> 6, c = e & 63;
    ST[g * 65 + c] = tok[(size_t)h * 4096 + e] / (nrm[h * 64 + g] + 1e-5f);
  }
  __syncthreads();
  for (int e = t; e < 4096; e += 256) {
    const int k = e >> 6, c = e & 63;
    float sy = 0.f, sv = 0.f;
    const float* mrow = mqk + c * 64;
    const float* wrow = Wv + c * 64;
#pragma unroll
    for (int c2 = 0; c2 < 64; ++c2) {
      const float st2 = ST[k * 65 + c2];
      sy = fmaf(mrow[c2], st2, sy);
      sv = fmaf(wrow[c2], st2, sv);
    }
    YL[k * 64 + c] = sy;
    VL[k * 64 + c] = sv;
  }
  __syncthreads();
  const int g = t & 63, kp = t >> 6;
  float z[16];
#pragma unroll
  for (int j = 0; j < 16; ++j) z[j] = 0.f;
  for (int c = 0; c < 64; ++c) {
    const float sg = ST[g * 65 + c];
#pragma unroll
    for (int j = 0; j < 16; ++j) z[j] = fmaf(sg, YL[(kp * 16 + j) * 64 + c], z[j]);
  }
  float m = z[0];
#pragma unroll
  for (int j = 1; j < 16; ++j) m = fmaxf(m, z[j]);
  red[kp][g] = m;
  __syncthreads();
  m = fmaxf(fmaxf(red[0][g], red[1][g]), fmaxf(red[2][g], red[3][g]));
  float ssum = 0.f;
#pragma unroll
  for (int j = 0; j < 16; ++j) {
    z[j] = __expf(z[j] - m);
    ssum += z[j];
  }
  red[4 + kp][g] = ssum;
  __syncthreads();
  ssum = red[4][g] + red[5][g] + red[6][g] + red[7][g];
  const float inv = 1.f / ssum;
#pragma unroll
  for (int j = 0; j < 16; ++j) ST[(kp * 16 + j) * 65 + g] = z[j] * inv;
  __syncthreads();
  for (int e = t; e < 4096; e += 256) {
    const int gg = e >> 6, d = e & 63;
    float s = 0.f;
#pragma unroll
    for (int k = 0; k < 64; ++k) s = fmaf(ST[k * 65 + gg], VL[k * 64 + d], s);
    YL[gg * 64 + d] = s;
  }
  __syncthreads();
  for (int e = t; e < 8192; e += 256) {
    const int o = e & 127, gg = e >> 7;
    float s = 0.f;
    const float* wrow = Wo + (size_t)o * INNER_ + h * 64;
#pragma unroll
    for (int d = 0; d < 64; ++d) s = fmaf(YL[gg * 64 + d], wrow[d], s);
    ushort hh, ll;
    split_bf16(s, hh, ll);
    const int hg = h * 64 + gg;
    const int kg2 = hg >> 3, kr = hg & 7;
    mht[((size_t)kg2 * 128 + o) * 8 + kr] = hh;
    mlt[((size_t)kg2 * 128 + o) * 8 + kr] = ll;
  }
}

// out[n][o] = sum_k w[n][k]*Mcat[k][o] + bo[o]; bf16x3 MFMA. grid (256, NB).
__global__ __launch_bounds__(256) void fused_out_kernel(
    const unsigned int* __restrict__ wp,
    const ushort* __restrict__ mht,
    const ushort* __restrict__ mlt,
    const float* __restrict__ bo,
    float* __restrict__ out) {
  __shared__ __align__(16) ushort lds[24576];
  const int bz = blockIdx.y;
  wp += (size_t)bz * N_ * INNER_;
  mht += (size_t)bz * (INNER_ * DIM_);
  mlt += (size_t)bz * (INNER_ * DIM_);
  out += (size_t)bz * N_ * DIM_;
  const int t = threadIdx.x;
  const int lane = t & 63;
  const int wid = t >> 6;
  const int wm = wid & 1, wn = wid >> 1;
  const int col = lane & 15, quad = lane >> 4;
  const int n0 = blockIdx.x * 64;

  vf4 acc[2][4];
#pragma unroll
  for (int m = 0; m < 2; ++m)
#pragma unroll
    for (int n = 0; n < 4; ++n) acc[m][n] = vf4{0.f, 0.f, 0.f, 0.f};

  for (int kc = 0; kc < 8; ++kc) {
    __syncthreads();
#pragma unroll
    for (int r = 0; r < 2; ++r) {
      const int row = r * 256 + t;
      const int pix = row >> 3, kg2 = row & 7;
      const unsigned int* gp = wp + (size_t)(n0 + pix) * INNER_ + kc * 64 + kg2 * 8;
      const uint4 p0 = *reinterpret_cast<const uint4*>(gp);
      const uint4 p1 = *reinterpret_cast<const uint4*>(gp + 4);
      unsigned int u[8] = {p0.x, p0.y, p0.z, p0.w, p1.x, p1.y, p1.z, p1.w};
      sh8 hv, lv;
#pragma unroll
      for (int j = 0; j < 8; ++j) {
        hv[j] = (short)(u[j] >> 16);
        lv[j] = (short)(u[j] & 0xffff);
      }
      const int drow = pix * 8 + (kg2 ^ (pix & 7));
      *reinterpret_cast<sh8*>(lds + drow * 8) = hv;
      *reinterpret_cast<sh8*>(lds + 4096 + drow * 8) = lv;
    }
#pragma unroll
    for (int r = 0; r < 4; ++r) {
      gload16(mht + (size_t)kc * 8192 + ((size_t)r * 256 + t) * 8, lds + 8192 + r * 2048 + t * 8);
      gload16(mlt + (size_t)kc * 8192 + ((size_t)r * 256 + t) * 8, lds + 16384 + r * 2048 + t * 8);
    }
    __syncthreads();
#pragma unroll
    for (int kk = 0; kk < 2; ++kk) {
      const int kg2 = kk * 4 + quad;
      sh8 ah[2], al[2], bh[4], bl[4];
#pragma unroll
      for (int m = 0; m < 2; ++m) {
        const int pix = wm * 32 + m * 16 + col;
        const int drow = pix * 8 + (kg2 ^ (pix & 7));
        ah[m] = *reinterpret_cast<const sh8*>(lds + drow * 8);
        al[m] = *reinterpret_cast<const sh8*>(lds + 4096 + drow * 8);
      }
#pragma unroll
      for (int n = 0; n < 4; ++n) {
        const int o = wn * 64 + n * 16 + col;
        bh[n] = *reinterpret_cast<const sh8*>(lds + 8192 + ((size_t)kg2 * 128 + o) * 8);
        bl[n] = *reinterpret_cast<const sh8*>(lds + 16384 + ((size_t)kg2 * 128 + o) * 8);
      }
      __builtin_amdgcn_s_setprio(1);
#pragma unroll
      for (int m = 0; m < 2; ++m)
#pragma unroll
        for (int n = 0; n < 4; ++n) {
          acc[m][n] = __builtin_amdgcn_mfma_f32_16x16x32_bf16(ah[m], bh[n], acc[m][n], 0, 0, 0);
          acc[m][n] = __builtin_amdgcn_mfma_f32_16x16x32_bf16(ah[m], bl[n], acc[m][n], 0, 0, 0);
          acc[m][n] = __builtin_amdgcn_mfma_f32_16x16x32_bf16(al[m], bh[n], acc[m][n], 0, 0, 0);
        }
      __builtin_amdgcn_s_setprio(0);
    }
  }
#pragma unroll
  for (int n = 0; n < 4; ++n) {
    const int o = wn * 64 + n * 16 + col;
    const float bv = bo[o];
#pragma unroll
    for (int m = 0; m < 2; ++m) {
#pragma unroll
      for (int r = 0; r < 4; ++r) {
        const int pix = wm * 32 + m * 16 + quad * 4 + r;
        out[(size_t)(n0 + pix) * DIM_ + o] = acc[m][n][r] + bv;
      }
    }
  }
}

extern "C" void kernel_launch(void* const* d_in, const int* in_sizes, int n_in,
                              void* d_out, int out_size, void* d_ws, size_t ws_size,
                              hipStream_t stream) {
  const float* x    = (const float*)d_in[0];
  const float* temp = (const float*)d_in[1];
  const float* Wx   = (const float*)d_in[2];
  const float* bx   = (const float*)d_in[3];
  const float* Wfx  = (const float*)d_in[4];
  const float* bfx  = (const float*)d_in[5];
  const float* Ws   = (const float*)d_in[6];
  const float* bs   = (const float*)d_in[7];
  const float* Wq   = (const float*)d_in[8];
  const float* Wk   = (const float*)d_in[9];
  const float* Wv   = (const float*)d_in[10];
  const float* Wo   = (const float*)d_in[11];
  const float* bo   = (const float*)d_in[12];
  float* out = (float*)d_out;

  // Workspace need as a function of batches-per-launch nb.
  auto need = [](int nb) -> size_t {
    size_t s = 0;
    s += 2 * (size_t)WT_PLANE * 2;                 // WTH/WTL
    s += 2 * (size_t)nb * XPT_PLANE * 2;           // XPTH/XPTL
    s += 2 * (size_t)nb * N_ * INNER_ * 4;         // LG/FXO
    s += (size_t)B_ * HEADS_ * G_ * DH_ * 4;       // TOK (always full B_)
    s += (size_t)B_ * HEADS_ * G_ * 4;             // NRM
    s += (size_t)DH_ * DH_ * 4;                    // MQK
    s += (size_t)INNER_ * 4;                       // BC
    s += 2 * (size_t)nb * INNER_ * DIM_ * 2;       // MHT/MLT
    s += (size_t)nb * 512 * 4096 * 4;              // TP
    s += (size_t)nb * 512 * 64 * 4;                // NP
    return s;
  };
  int nb = 1;
  if (ws_size >= need(4)) nb = 4;
  else if (ws_size >= need(2)) nb = 2;

  char* p = (char*)d_ws;
  ushort* WTH = (ushort*)p; p += (size_t)WT_PLANE * 2;
  ushort* WTL = (ushort*)p; p += (size_t)WT_PLANE * 2;
  ushort* XPTH = (ushort*)p; p += (size_t)nb * XPT_PLANE * 2;
  ushort* XPTL = (ushort*)p; p += (size_t)nb * XPT_PLANE * 2;
  float* LG  = (float*)p; p += (size_t)nb * N_ * INNER_ * 4;   // logits -> packed w
  float* FXO = (float*)p; p += (size_t)nb * N_ * INNER_ * 4;   // fx_mid
  float* TOK = (float*)p; p += (size_t)B_ * HEADS_ * G_ * DH_ * 4;
  float* NRM = (float*)p; p += (size_t)B_ * HEADS_ * G_ * 4;
  float* MQK = (float*)p; p += (size_t)DH_ * DH_ * 4;
  float* BC  = (float*)p; p += (size_t)INNER_ * 4;
  ushort* MHT = (ushort*)p; p += (size_t)nb * INNER_ * DIM_ * 2;
  ushort* MLT = (ushort*)p; p += (size_t)nb * INNER_ * DIM_ * 2;
  float* TP  = (float*)p; p += (size_t)nb * 512 * 4096 * 4;    // token partials
  float* NP  = (float*)p; p += (size_t)nb * 512 * 64 * 4;      // norm partials

  wfx_kernel<<<2304, 256, 0, stream>>>(Wfx, WTH, WTL);
  wcomp_kernel<<<dim3(9, 8), 256, 0, stream>>>(Wx, Ws, bx, bs, temp, WTH, WTL, BC);
  mqk_kernel<<<16, 256, 0, stream>>>(Wq, Wk, MQK);

  for (int b0 = 0; b0 < B_; b0 += nb) {
    const float* xb = x + (size_t)b0 * N_ * DIM_;
    float* outb = out + (size_t)b0 * N_ * DIM_;
    float* tokb = TOK + (size_t)b0 * HEADS_ * G_ * DH_;
    float* nrmb = NRM + (size_t)b0 * HEADS_ * G_;

    pad_tile_kernel<<<dim3(8515, nb), 256, 0, stream>>>(xb, XPTH, XPTL);
    conv_mfma_kernel<<<dim3(8, 128, nb), 256, 0, stream>>>(XPTH, XPTL, WTH, WTL, BC, bfx, LG, FXO);
    slice_kernel<<<dim3(512, nb), 256, 0, stream>>>(LG, FXO, TP, NP);
    reduce_kernel<<<dim3(129, nb), 256, 0, stream>>>(TP, NP, tokb, nrmb);
    head_kernel<<<dim3(8, nb), 256, 0, stream>>>(tokb, nrmb, MQK, Wv, Wo, MHT, MLT);
    fused_out_kernel<<<dim3(256, nb), 256, 0, stream>>>((const unsigned int*)LG, MHT, MLT, bo, outb);
  }
}